// Round 7
// baseline (565.419 us; speedup 1.0000x reference)
//
#include <hip/hip_runtime.h>

#define BB 16
#define NN 4096
#define NPOINTS 1024
#define KK 32
#define NPTS (BB*NPOINTS)        // 16384
#define NWN  (BB*NPOINTS*KK)     // 524288
#define EPSF 1e-5f

typedef unsigned short u16;
typedef u16  u16x8 __attribute__((ext_vector_type(8)));
typedef short s16x8 __attribute__((ext_vector_type(8)));
typedef float f32x4 __attribute__((ext_vector_type(4)));

__device__ __forceinline__ float bf(u16 u){
  union { unsigned int i; float f; } v; v.i = ((unsigned int)u) << 16; return v.f;
}
__device__ __forceinline__ u16 f2b(float f){
  union { float ff; unsigned int i; } v; v.ff = f;
  unsigned int r = v.i + 0x7FFFu + ((v.i >> 16) & 1u);
  return (u16)(r >> 16);
}

// ---------------- K0: new_xyz gather (f32 copy) ----------------
__global__ __launch_bounds__(256) void k_newxyz(const float* xyz, const int* didx, float* out){
  int p = blockIdx.x * 256 + threadIdx.x;
  if (p >= NPTS) return;
  int b = p >> 10;
  int idx = didx[p];
  const float* src = xyz + ((size_t)(b * NN + idx)) * 3;
  float* dst = out + (size_t)p * 3;
  dst[0] = src[0]; dst[1] = src[1]; dst[2] = src[2];
}

// ---------------- k_prep: lwbt[o][ch] = bf16(lw[ch][o]) ----------------
__global__ __launch_bounds__(256) void k_prep(const float* lw, u16* lwbt){
  __shared__ float T[64][65];
  int t = threadIdx.x;
  int kb = blockIdx.x * 64;
  {
    int k = t >> 2, c4 = t & 3;
    #pragma unroll
    for (int j = 0; j < 4; ++j)
      *(f32x4*)&T[k][c4*16 + j*4] = *(const f32x4*)(lw + (size_t)(kb + k)*64 + c4*16 + j*4);
  }
  __syncthreads();
  {
    int n = t >> 2, k4 = t & 3;
    u16x8 o0, o1;
    #pragma unroll
    for (int j = 0; j < 8; ++j) o0[j] = f2b(T[k4*16 + j][n]);
    #pragma unroll
    for (int j = 0; j < 8; ++j) o1[j] = f2b(T[k4*16 + 8 + j][n]);
    *(u16x8*)(lwbt + (size_t)n*4096 + kb + k4*16)     = o0;
    *(u16x8*)(lwbt + (size_t)n*4096 + kb + k4*16 + 8) = o1;
  }
}

// ---------------- k_stat0: raw-lc moments (3-dim Gram) ----------------
__global__ __launch_bounds__(256) void k_stat0(const float* lc, float* PA){
  int t = threadIdx.x;
  float a[9];
  #pragma unroll
  for (int r = 0; r < 9; ++r) a[r] = 0.f;
  size_t base = (size_t)blockIdx.x * 1024 + t;
  for (int ip = 0; ip < 4; ++ip){
    size_t p = base + (size_t)ip * 256;
    float x0 = lc[p*3], x1 = lc[p*3+1], x2 = lc[p*3+2];
    a[0]+=x0; a[1]+=x1; a[2]+=x2;
    a[3]+=x0*x0; a[4]+=x0*x1; a[5]+=x0*x2;
    a[6]+=x1*x1; a[7]+=x1*x2; a[8]+=x2*x2;
  }
  #pragma unroll
  for (int m = 1; m < 64; m <<= 1){
    #pragma unroll
    for (int r = 0; r < 9; ++r) a[r] += __shfl_xor(a[r], m);
  }
  if ((t & 63) == 0){
    float* dst = PA + (size_t)(blockIdx.x*4 + (t>>6)) * 16;
    f32x4 v0 = {a[0],a[1],a[2],a[3]}, v1 = {a[4],a[5],a[6],a[7]}, v2 = {a[8],0.f,0.f,0.f};
    *(f32x4*)dst = v0; *(f32x4*)(dst+4) = v1; *(f32x4*)(dst+8) = v2;
  }
}

// ---------------- k_red0: finalize layer0 BN from lc moments ----------------
__global__ __launch_bounds__(256) void k_red0(const float* PA, const float* w0, const float* b0,
                                              const float* g0, const float* be0, float* AD){
  __shared__ float ms[12];
  int t = threadIdx.x;
  if (t < 12){
    float s0=0,s1=0,s2=0,s3=0;
    const float* p = PA + t;
    for (int r = 0; r < 2048; r += 4){
      s0 += p[(size_t)(r+0)*16]; s1 += p[(size_t)(r+1)*16];
      s2 += p[(size_t)(r+2)*16]; s3 += p[(size_t)(r+3)*16];
    }
    ms[t] = (s0+s1)+(s2+s3);
  }
  __syncthreads();
  if (t < 16){
    float wx = w0[t*3], wy = w0[t*3+1], wz = w0[t*3+2], bb = b0[t];
    float lin = wx*ms[0] + wy*ms[1] + wz*ms[2];
    float quad = wx*wx*ms[3] + wy*wy*ms[6] + wz*wz*ms[8]
               + 2.f*(wx*wy*ms[4] + wx*wz*ms[5] + wy*wz*ms[7]);
    float S = lin + (float)NWN * bb;
    float Q = quad + 2.f*bb*lin + (float)NWN*bb*bb;
    float m = S * (1.f/NWN);
    float v = Q * (1.f/NWN) - m*m;
    float a = g0[t] * rsqrtf(v + EPSF);
    AD[t] = a; AD[16+t] = be0[t] - m*a;
  }
}

// ---------------- k_stat1: h0 sums + 16-dim Gram ----------------
__global__ __launch_bounds__(256,2) void k_stat1(const float* lc, const float* w0, const float* b0,
                                                 const float* AD, float* PB){
  __shared__ f32x4 w0p[16];
  __shared__ float a0s[16], d0s[16];
  int t = threadIdx.x;
  if (t < 16){
    f32x4 wv = {w0[t*3], w0[t*3+1], w0[t*3+2], b0[t]};
    w0p[t] = wv;
    a0s[t] = AD[t]; d0s[t] = AD[16+t];
  }
  __syncthreads();
  float G[136], sh[16];
  #pragma unroll
  for (int r = 0; r < 136; ++r) G[r] = 0.f;
  #pragma unroll
  for (int r = 0; r < 16; ++r) sh[r] = 0.f;
  size_t base = (size_t)blockIdx.x * 1024 + t;
  for (int ip = 0; ip < 4; ++ip){
    size_t p = base + (size_t)ip * 256;
    float x0 = lc[p*3], x1 = lc[p*3+1], x2 = lc[p*3+2];
    float h[16];
    #pragma unroll
    for (int oc = 0; oc < 16; ++oc){
      f32x4 w = w0p[oc];
      float y = w.x*x0 + w.y*x1 + w.z*x2 + w.w;
      h[oc] = fmaxf(0.f, a0s[oc]*y + d0s[oc]);
      sh[oc] += h[oc];
    }
    int idx = 0;
    #pragma unroll
    for (int i = 0; i < 16; ++i){
      #pragma unroll
      for (int j = i; j < 16; ++j){ G[idx] += h[i]*h[j]; ++idx; }
    }
  }
  #pragma unroll
  for (int m = 1; m < 64; m <<= 1){
    #pragma unroll
    for (int r = 0; r < 136; ++r) G[r] += __shfl_xor(G[r], m);
    #pragma unroll
    for (int r = 0; r < 16; ++r) sh[r] += __shfl_xor(sh[r], m);
  }
  if ((t & 63) == 0){
    float* dst = PB + (size_t)(blockIdx.x*4 + (t>>6)) * 160;
    #pragma unroll
    for (int r = 0; r < 136; r += 4){ f32x4 v = {G[r],G[r+1],G[r+2],G[r+3]}; *(f32x4*)(dst + r) = v; }
    #pragma unroll
    for (int r = 0; r < 16; r += 4){ f32x4 v = {sh[r],sh[r+1],sh[r+2],sh[r+3]}; *(f32x4*)(dst + 136 + r) = v; }
  }
}

// ---------------- k_red1: reduce h0 Gram -> layer1 BN params ----------------
__global__ __launch_bounds__(256) void k_red1(const float* PB, const float* w1, const float* b1,
                                              const float* g1, const float* be1, float* AD){
  __shared__ float red[152];
  int t = threadIdx.x;
  if (t < 152){
    float s0=0,s1=0,s2=0,s3=0,s4=0,s5=0,s6=0,s7=0;
    const float* p = PB + t;
    for (int r = 0; r < 2048; r += 8){
      s0 += p[(size_t)(r+0)*160]; s1 += p[(size_t)(r+1)*160];
      s2 += p[(size_t)(r+2)*160]; s3 += p[(size_t)(r+3)*160];
      s4 += p[(size_t)(r+4)*160]; s5 += p[(size_t)(r+5)*160];
      s6 += p[(size_t)(r+6)*160]; s7 += p[(size_t)(r+7)*160];
    }
    red[t] = ((s0+s1)+(s2+s3)) + ((s4+s5)+(s6+s7));
  }
  __syncthreads();
  if (t < 16){
    float wv[16];
    #pragma unroll
    for (int ic = 0; ic < 16; ++ic) wv[ic] = w1[t*16+ic];
    float lin = 0.f;
    #pragma unroll
    for (int ic = 0; ic < 16; ++ic) lin += wv[ic]*red[136+ic];
    float quad = 0.f; int idx = 0;
    for (int i = 0; i < 16; ++i)
      for (int j = i; j < 16; ++j){
        float M = red[idx++];
        quad += wv[i]*wv[j]*M*((i==j)?1.f:2.f);
      }
    float bb = b1[t];
    float S = lin + (float)NWN * bb;
    float Q = quad + 2.f*bb*lin + (float)NWN*bb*bb;
    float m = S * (1.f/NWN);
    float v = Q * (1.f/NWN) - m*m;
    float a = g1[t] * rsqrtf(v + EPSF);
    AD[32+t] = a; AD[48+t] = be1[t] - m*a;
  }
}

// ---------------- k_stat2: h1 sums + 16-dim Gram ----------------
__global__ __launch_bounds__(256,2) void k_stat2(const float* lc, const float* w0, const float* b0,
                                                 const float* w1, const float* b1,
                                                 const float* AD, float* PB){
  __shared__ f32x4 w0p[16];
  __shared__ float a0s[16], d0s[16];
  __shared__ float w1s[256];
  __shared__ float b1s[16], a1s[16], d1s[16];
  int t = threadIdx.x;
  if (t < 16){
    f32x4 wv = {w0[t*3], w0[t*3+1], w0[t*3+2], b0[t]};
    w0p[t] = wv;
    a0s[t] = AD[t]; d0s[t] = AD[16+t];
    b1s[t] = b1[t]; a1s[t] = AD[32+t]; d1s[t] = AD[48+t];
  }
  w1s[t] = w1[t];
  __syncthreads();
  float G[136], sh[16];
  #pragma unroll
  for (int r = 0; r < 136; ++r) G[r] = 0.f;
  #pragma unroll
  for (int r = 0; r < 16; ++r) sh[r] = 0.f;
  size_t base = (size_t)blockIdx.x * 1024 + t;
  for (int ip = 0; ip < 4; ++ip){
    size_t p = base + (size_t)ip * 256;
    float x0 = lc[p*3], x1 = lc[p*3+1], x2 = lc[p*3+2];
    float h0[16];
    #pragma unroll
    for (int oc = 0; oc < 16; ++oc){
      f32x4 w = w0p[oc];
      float y = w.x*x0 + w.y*x1 + w.z*x2 + w.w;
      h0[oc] = fmaxf(0.f, a0s[oc]*y + d0s[oc]);
    }
    float h[16];
    #pragma unroll
    for (int oc = 0; oc < 16; ++oc){
      const f32x4* wr = (const f32x4*)&w1s[oc*16];
      f32x4 wa = wr[0], wb = wr[1], wc = wr[2], wd = wr[3];
      float y = b1s[oc];
      y += wa.x*h0[0]  + wa.y*h0[1]  + wa.z*h0[2]  + wa.w*h0[3];
      y += wb.x*h0[4]  + wb.y*h0[5]  + wb.z*h0[6]  + wb.w*h0[7];
      y += wc.x*h0[8]  + wc.y*h0[9]  + wc.z*h0[10] + wc.w*h0[11];
      y += wd.x*h0[12] + wd.y*h0[13] + wd.z*h0[14] + wd.w*h0[15];
      h[oc] = fmaxf(0.f, a1s[oc]*y + d1s[oc]);
      sh[oc] += h[oc];
    }
    int idx = 0;
    #pragma unroll
    for (int i = 0; i < 16; ++i){
      #pragma unroll
      for (int j = i; j < 16; ++j){ G[idx] += h[i]*h[j]; ++idx; }
    }
  }
  #pragma unroll
  for (int m = 1; m < 64; m <<= 1){
    #pragma unroll
    for (int r = 0; r < 136; ++r) G[r] += __shfl_xor(G[r], m);
    #pragma unroll
    for (int r = 0; r < 16; ++r) sh[r] += __shfl_xor(sh[r], m);
  }
  if ((t & 63) == 0){
    float* dst = PB + (size_t)(blockIdx.x*4 + (t>>6)) * 160;
    #pragma unroll
    for (int r = 0; r < 136; r += 4){ f32x4 v = {G[r],G[r+1],G[r+2],G[r+3]}; *(f32x4*)(dst + r) = v; }
    #pragma unroll
    for (int r = 0; r < 16; r += 4){ f32x4 v = {sh[r],sh[r+1],sh[r+2],sh[r+3]}; *(f32x4*)(dst + 136 + r) = v; }
  }
}

// ---------------- k_red2: reduce h1 Gram -> layer2 BN params ----------------
__global__ __launch_bounds__(256) void k_red2(const float* PB, const float* w2, const float* b2,
                                              const float* g2, const float* be2, float* AD){
  __shared__ float red[152];
  int t = threadIdx.x;
  if (t < 152){
    float s0=0,s1=0,s2=0,s3=0,s4=0,s5=0,s6=0,s7=0;
    const float* p = PB + t;
    for (int r = 0; r < 2048; r += 8){
      s0 += p[(size_t)(r+0)*160]; s1 += p[(size_t)(r+1)*160];
      s2 += p[(size_t)(r+2)*160]; s3 += p[(size_t)(r+3)*160];
      s4 += p[(size_t)(r+4)*160]; s5 += p[(size_t)(r+5)*160];
      s6 += p[(size_t)(r+6)*160]; s7 += p[(size_t)(r+7)*160];
    }
    red[t] = ((s0+s1)+(s2+s3)) + ((s4+s5)+(s6+s7));
  }
  __syncthreads();
  if (t < 64){
    float wv[16];
    #pragma unroll
    for (int ic = 0; ic < 16; ++ic) wv[ic] = w2[t*16+ic];
    float lin = 0.f;
    #pragma unroll
    for (int ic = 0; ic < 16; ++ic) lin += wv[ic]*red[136+ic];
    float quad = 0.f; int idx = 0;
    for (int i = 0; i < 16; ++i)
      for (int j = i; j < 16; ++j){
        float M = red[idx++];
        quad += wv[i]*wv[j]*M*((i==j)?1.f:2.f);
      }
    float bb = b2[t];
    float S = lin + (float)NWN * bb;
    float Q = quad + 2.f*bb*lin + (float)NWN*bb*bb;
    float m = S * (1.f/NWN);
    float v = Q * (1.f/NWN) - m*m;
    float a = g2[t] * rsqrtf(v + EPSF);
    AD[64+t] = a; AD[128+t] = be2[t] - m*a;
  }
}

// ---------------- K5: one point per block — gather + WeightNet + MFMA ----------------
__global__ __launch_bounds__(256) void k_main(const float* lcg, const int* nbrg,
    const float* points, const float* xyz,
    const float* w0, const float* b0, const float* w1, const float* b1,
    const float* w2, const float* b2, const float* AD,
    u16* npw){
  __shared__ u16   Gr[32*72];          // bf16 row-major: Gr[k][i], stride 72
  __shared__ u16   Wr[32*72];          // bf16 row-major: Wr[k][o], stride 72
  __shared__ float H0s[32][17];
  __shared__ float H1s[32][20];        // stride 20 -> 16B-aligned f32x4 rows
  __shared__ float lcs[32][4];
  __shared__ int   nbr[32];
  __shared__ float w0c[48], b0c[16], a0c[16], d0c[16];
  __shared__ float w1c[16][17], b1c[16], a1c[16], d1c[16];
  __shared__ float w2c[64][17], b2c[64], a2c[64], d2c[64];
  int t = threadIdx.x;
  int point = blockIdx.x;
  int bb = point >> 10;
  if (t < 48) w0c[t] = w0[t];
  if (t < 16){
    b0c[t] = b0[t]; b1c[t] = b1[t];
    a0c[t] = AD[t];    d0c[t] = AD[16+t];
    a1c[t] = AD[32+t]; d1c[t] = AD[48+t];
  }
  w1c[t>>4][t&15] = w1[t];
  for (int i = t; i < 1024; i += 256) w2c[i>>4][i&15] = w2[i];
  if (t < 64){
    b2c[t] = b2[t];
    a2c[t] = AD[64+t]; d2c[t] = AD[128+t];
  }
  if (t < 32) nbr[t] = nbrg[(size_t)point * 32 + t];
  if (t < 96){ int k = t / 3, c = t % 3; lcs[k][c] = lcg[(size_t)point * 96 + t]; }
  __syncthreads();   // (A) weights + nbr + lcs ready

  // gather grouped -> Gr bf16 (coalesced row writes)
  {
    int k = t >> 3, c8 = t & 7;
    int n = nbr[k];
    const float* prow = points + (size_t)(bb * NN + n) * 61;
    const float* xr   = xyz    + (size_t)(bb * NN + n) * 3;
    u16x8 g;
    #pragma unroll
    for (int j = 0; j < 8; ++j){
      int c = c8 * 8 + j;
      g[j] = f2b((c < 61) ? prow[c] : xr[c - 61]);
    }
    *(u16x8*)&Gr[k*72 + c8*8] = g;
  }
  // H0
  #pragma unroll
  for (int jj = 0; jj < 2; ++jj){
    int l2 = t + jj * 256; int k = l2 >> 4, oc = l2 & 15;
    float y = w0c[oc*3]*lcs[k][0] + w0c[oc*3+1]*lcs[k][1] + w0c[oc*3+2]*lcs[k][2] + b0c[oc];
    H0s[k][oc] = fmaxf(0.f, a0c[oc]*y + d0c[oc]);
  }
  __syncthreads();   // (B) H0 ready
  // H1
  #pragma unroll
  for (int jj = 0; jj < 2; ++jj){
    int l2 = t + jj * 256; int k = l2 >> 4, oc = l2 & 15;
    float y = b1c[oc];
    #pragma unroll
    for (int ic = 0; ic < 16; ++ic) y += w1c[oc][ic] * H0s[k][ic];
    H1s[k][oc] = fmaxf(0.f, a1c[oc]*y + d1c[oc]);
  }
  __syncthreads();   // (C) H1 ready
  // W -> Wr
  {
    int o = t & 63, kb = (t >> 6) * 8;
    float wrow[16];
    #pragma unroll
    for (int ic = 0; ic < 16; ++ic) wrow[ic] = w2c[o][ic];
    float a2 = a2c[o], d2 = d2c[o], bb2 = b2c[o];
    #pragma unroll
    for (int j = 0; j < 8; ++j){
      const f32x4* hr = (const f32x4*)&H1s[kb + j][0];
      f32x4 h0v = hr[0], h1v = hr[1], h2v = hr[2], h3v = hr[3];
      float y = bb2;
      y += wrow[0]*h0v.x + wrow[1]*h0v.y + wrow[2]*h0v.z + wrow[3]*h0v.w;
      y += wrow[4]*h1v.x + wrow[5]*h1v.y + wrow[6]*h1v.z + wrow[7]*h1v.w;
      y += wrow[8]*h2v.x + wrow[9]*h2v.y + wrow[10]*h2v.z + wrow[11]*h2v.w;
      y += wrow[12]*h3v.x + wrow[13]*h3v.y + wrow[14]*h3v.z + wrow[15]*h3v.w;
      Wr[(kb + j)*72 + o] = f2b(fmaxf(0.f, a2*y + d2));
    }
  }
  __syncthreads();   // (D) Gr, Wr ready
  // MFMA: wave w owns o-tile w; all 4 i-tiles; direct global store
  {
    int w = t >> 6, l = t & 63;
    int li = l & 15, lk = (l >> 4) * 8, lr = (l >> 4) * 4;
    s16x8 bfrag;
    #pragma unroll
    for (int j = 0; j < 8; ++j) bfrag[j] = (short)Wr[(lk + j)*72 + w*16 + li];
    #pragma unroll
    for (int it = 0; it < 4; ++it){
      s16x8 afrag;
      #pragma unroll
      for (int j = 0; j < 8; ++j) afrag[j] = (short)Gr[(lk + j)*72 + it*16 + li];
      f32x4 z = {0.f, 0.f, 0.f, 0.f};
      f32x4 d = __builtin_amdgcn_mfma_f32_16x16x32_bf16(afrag, bfrag, z, 0, 0, 0);
      #pragma unroll
      for (int r = 0; r < 4; ++r)
        npw[(size_t)point*4096 + (size_t)(it*16 + lr + r)*64 + w*16 + li] = f2b(d[r]);
    }
  }
}

// ---------------- K5b: channel stats from npw (streaming, coalesced) ----------------
__global__ __launch_bounds__(256) void k_statC(const u16* npw, float* PC){
  int t = threadIdx.x;
  float s[16], q[16];
  #pragma unroll
  for (int j = 0; j < 16; ++j){ s[j] = 0.f; q[j] = 0.f; }
  size_t rowbase = (size_t)blockIdx.x * 64;
  for (int p = 0; p < 64; ++p){
    const u16* row = npw + (rowbase + p) * 4096 + t * 16;
    u16x8 a = *(const u16x8*)row;
    u16x8 b = *(const u16x8*)(row + 8);
    #pragma unroll
    for (int j = 0; j < 8; ++j){ float v = bf(a[j]); s[j]   += v; q[j]   += v*v; }
    #pragma unroll
    for (int j = 0; j < 8; ++j){ float v = bf(b[j]); s[8+j] += v; q[8+j] += v*v; }
  }
  float* dst = PC + (size_t)blockIdx.x * 8192 + t * 16;
  #pragma unroll
  for (int j = 0; j < 16; ++j){ dst[j] = s[j]; dst[4096 + j] = q[j]; }
}

// ---------------- K6b: reduce partials + finalize 4096-channel BN ----------------
__global__ __launch_bounds__(256) void k_finC(const float* PC, const float* gc, const float* bc,
                                              float* AC, float* DC){
  int ch = blockIdx.x * 256 + threadIdx.x;
  float s = 0.f, q = 0.f;
  for (int r = 0; r < 256; ++r){
    s += PC[(size_t)r * 8192 + ch];
    q += PC[(size_t)r * 8192 + 4096 + ch];
  }
  float m = s * (1.f/16384.f);
  float v = q * (1.f/16384.f) - m*m;
  float a = gc[ch] * rsqrtf(v + EPSF);
  AC[ch] = a; DC[ch] = bc[ch] - m*a;
}

// ---------------- K7: MFMA GEMM [16384,4096]x[4096,64], fused bn+relu on A ----------------
__global__ __launch_bounds__(256) void k_linear(const u16* npw, const float* AC, const float* DC,
                                                const u16* lwbt, const float* lb, float* yw){
  __shared__ u16 Al[32*72];
  __shared__ u16 Bl[64*72];
  int t = threadIdx.x;
  int w = t >> 6, l = t & 63;
  int rowbase = blockIdx.x * 32;
  int mt = w & 1, np2 = w >> 1;
  f32x4 acc0 = {0.f,0.f,0.f,0.f}, acc1 = acc0;
  for (int kb = 0; kb < 4096; kb += 64){
    __syncthreads();
    {
      int r = t >> 3, c8 = t & 7;
      int kk = kb + c8*8;
      u16x8 u = *(const u16x8*)(npw + (size_t)(rowbase + r)*4096 + kk);
      f32x4 alo = *(const f32x4*)(AC + kk), ahi = *(const f32x4*)(AC + kk + 4);
      f32x4 dlo = *(const f32x4*)(DC + kk), dhi = *(const f32x4*)(DC + kk + 4);
      u16x8 o;
      o[0] = f2b(fmaxf(0.f, alo.x*bf(u[0]) + dlo.x));
      o[1] = f2b(fmaxf(0.f, alo.y*bf(u[1]) + dlo.y));
      o[2] = f2b(fmaxf(0.f, alo.z*bf(u[2]) + dlo.z));
      o[3] = f2b(fmaxf(0.f, alo.w*bf(u[3]) + dlo.w));
      o[4] = f2b(fmaxf(0.f, ahi.x*bf(u[4]) + dhi.x));
      o[5] = f2b(fmaxf(0.f, ahi.y*bf(u[5]) + dhi.y));
      o[6] = f2b(fmaxf(0.f, ahi.z*bf(u[6]) + dhi.z));
      o[7] = f2b(fmaxf(0.f, ahi.w*bf(u[7]) + dhi.w));
      *(u16x8*)&Al[r*72 + c8*8] = o;
    }
    #pragma unroll
    for (int jj = 0; jj < 2; ++jj){
      int n = (t >> 3) + jj*32, c8 = t & 7;
      u16x8 u = *(const u16x8*)(lwbt + (size_t)n*4096 + kb + c8*8);
      *(u16x8*)&Bl[n*72 + c8*8] = u;
    }
    __syncthreads();
    #pragma unroll
    for (int ks = 0; ks < 2; ++ks){
      s16x8 af  = *(const s16x8*)&Al[(mt*16 + (l & 15))*72 + ks*32 + (l >> 4)*8];
      s16x8 bf0 = *(const s16x8*)&Bl[((np2*2    )*16 + (l & 15))*72 + ks*32 + (l >> 4)*8];
      s16x8 bf1 = *(const s16x8*)&Bl[((np2*2 + 1)*16 + (l & 15))*72 + ks*32 + (l >> 4)*8];
      acc0 = __builtin_amdgcn_mfma_f32_16x16x32_bf16(af, bf0, acc0, 0, 0, 0);
      acc1 = __builtin_amdgcn_mfma_f32_16x16x32_bf16(af, bf1, acc1, 0, 0, 0);
    }
  }
  int col0 = np2*32 + (l & 15), col1 = col0 + 16;
  float lb0 = lb[col0], lb1 = lb[col1];
  #pragma unroll
  for (int r = 0; r < 4; ++r){
    int row = rowbase + mt*16 + (l >> 4)*4 + r;
    yw[(size_t)row*64 + col0] = acc0[r] + lb0;
    yw[(size_t)row*64 + col1] = acc1[r] + lb1;
  }
}

// ---------------- K8a: final-BN stats -> block partials ----------------
__global__ __launch_bounds__(256) void k_statL(const float* yw, float* PL){
  __shared__ float sh[4][128];
  int t = threadIdx.x;
  int o = t & 63;
  int w = t >> 6;
  int rg = blockIdx.x * 4 + w;
  float s = 0.f, q = 0.f;
  for (int r = rg * 64; r < rg * 64 + 64; ++r){
    float v = yw[(size_t)r * 64 + o];
    s += v; q += v*v;
  }
  sh[w][o] = s; sh[w][64+o] = q;
  __syncthreads();
  if (t < 128) PL[blockIdx.x*128 + t] = sh[0][t] + sh[1][t] + sh[2][t] + sh[3][t];
}

__global__ __launch_bounds__(128) void k_redL(const float* PL, float* SL){
  int t = threadIdx.x;
  float s = 0.f;
  for (int b = 0; b < 64; ++b) s += PL[b*128 + t];
  SL[t] = s;
}

__global__ __launch_bounds__(256) void k_final(const float* yw, const float* SL,
                                               const float* gl, const float* bl, float* out){
  int gid = blockIdx.x * 256 + threadIdx.x;
  int o = gid & 63;
  float m = SL[o] * (1.f/16384.f);
  float v = SL[64 + o] * (1.f/16384.f) - m*m;
  float a = gl[o] * rsqrtf(v + EPSF);
  float d = bl[o] - m*a;
  float y = fmaxf(0.f, a * yw[gid] + d);
  out[49152 + gid] = y;
}

extern "C" void kernel_launch(void* const* d_in, const int* in_sizes, int n_in,
                              void* d_out, int out_size, void* d_ws, size_t ws_size,
                              hipStream_t stream){
  (void)in_sizes; (void)n_in; (void)out_size; (void)ws_size;
  const float* xyz    = (const float*)d_in[0];
  const float* points = (const float*)d_in[1];
  const float* lc     = (const float*)d_in[2];
  const int*   nbrl   = (const int*)d_in[3];
  const int*   didx   = (const int*)d_in[4];
  const float* w0 = (const float*)d_in[5];
  const float* b0 = (const float*)d_in[6];
  const float* g0 = (const float*)d_in[7];
  const float* be0= (const float*)d_in[8];
  const float* w1 = (const float*)d_in[9];
  const float* b1 = (const float*)d_in[10];
  const float* g1 = (const float*)d_in[11];
  const float* be1= (const float*)d_in[12];
  const float* w2 = (const float*)d_in[13];
  const float* b2 = (const float*)d_in[14];
  const float* g2 = (const float*)d_in[15];
  const float* be2= (const float*)d_in[16];
  const float* gc = (const float*)d_in[17];
  const float* bc = (const float*)d_in[18];
  const float* lw = (const float*)d_in[19];
  const float* lb = (const float*)d_in[20];
  const float* gl = (const float*)d_in[21];
  const float* bl = (const float*)d_in[22];
  float* out = (float*)d_out;
  char* ws = (char*)d_ws;

  float* AD  = (float*)ws;           // 192
  float* SL  = AD + 192;             // 128
  float* AC  = SL + 128;             // 4096
  float* DC  = AC + 4096;            // 4096
  float* PL  = DC + 4096;            // 8192
  float* PA  = PL + 8192;            // 2048*16 = 32768
  float* PB1 = PA + 32768;           // 2048*160 = 327680
  float* PB2 = PB1 + 327680;         // 327680
  float* PC  = (float*)(ws + 4194304);                        // 8 MB
  u16*  npw  = (u16*)(ws + 4194304 + 8388608);                // 128 MB bf16
  float* yw  = (float*)(ws + 4194304 + 8388608 + 134217728);  // 4 MB f32
  u16*  lwbt = (u16*)(ws + 4194304 + 8388608 + 134217728 + 4194304); // 512 KB

  k_newxyz <<<64,    256, 0, stream>>>(xyz, didx, out);
  k_prep   <<<64,    256, 0, stream>>>(lw, lwbt);
  k_stat0  <<<512,   256, 0, stream>>>(lc, PA);
  k_red0   <<<1,     256, 0, stream>>>(PA, w0, b0, g0, be0, AD);
  k_stat1  <<<512,   256, 0, stream>>>(lc, w0, b0, AD, PB1);
  k_red1   <<<1,     256, 0, stream>>>(PB1, w1, b1, g1, be1, AD);
  k_stat2  <<<512,   256, 0, stream>>>(lc, w0, b0, w1, b1, AD, PB2);
  k_red2   <<<1,     256, 0, stream>>>(PB2, w2, b2, g2, be2, AD);
  k_main   <<<16384, 256, 0, stream>>>(lc, nbrl, points, xyz,
                                       w0, b0, w1, b1, w2, b2, AD, npw);
  k_statC  <<<256,   256, 0, stream>>>(npw, PC);
  k_finC   <<<16,    256, 0, stream>>>(PC, gc, bc, AC, DC);
  k_linear <<<512,   256, 0, stream>>>(npw, AC, DC, lwbt, lb, yw);
  k_statL  <<<64,    256, 0, stream>>>(yw, PL);
  k_redL   <<<1,     128, 0, stream>>>(PL, SL);
  k_final  <<<4096,  256, 0, stream>>>(yw, SL, gl, bl, out);
}

// Round 8
// 382.020 us; speedup vs baseline: 1.4801x; 1.4801x over previous
//
#include <hip/hip_runtime.h>

#define BB 16
#define NN 4096
#define NPOINTS 1024
#define KK 32
#define NPTS (BB*NPOINTS)        // 16384
#define NWN  (BB*NPOINTS*KK)     // 524288
#define EPSF 1e-5f

typedef unsigned short u16;
typedef u16  u16x8 __attribute__((ext_vector_type(8)));
typedef short s16x8 __attribute__((ext_vector_type(8)));
typedef float f32x4 __attribute__((ext_vector_type(4)));

__device__ __forceinline__ float bf(u16 u){
  union { unsigned int i; float f; } v; v.i = ((unsigned int)u) << 16; return v.f;
}
__device__ __forceinline__ u16 f2b(float f){
  union { float ff; unsigned int i; } v; v.ff = f;
  unsigned int r = v.i + 0x7FFFu + ((v.i >> 16) & 1u);
  return (u16)(r >> 16);
}

// ---------------- K0: new_xyz gather (f32 copy) ----------------
__global__ __launch_bounds__(256) void k_newxyz(const float* xyz, const int* didx, float* out){
  int p = blockIdx.x * 256 + threadIdx.x;
  if (p >= NPTS) return;
  int b = p >> 10;
  int idx = didx[p];
  const float* src = xyz + ((size_t)(b * NN + idx)) * 3;
  float* dst = out + (size_t)p * 3;
  dst[0] = src[0]; dst[1] = src[1]; dst[2] = src[2];
}

// ---------------- k_prep: lwbt[o][ch] = bf16(lw[ch][o]) ----------------
__global__ __launch_bounds__(256) void k_prep(const float* lw, u16* lwbt){
  __shared__ float T[64][65];
  int t = threadIdx.x;
  int kb = blockIdx.x * 64;
  {
    int k = t >> 2, c4 = t & 3;
    #pragma unroll
    for (int j = 0; j < 4; ++j)
      *(f32x4*)&T[k][c4*16 + j*4] = *(const f32x4*)(lw + (size_t)(kb + k)*64 + c4*16 + j*4);
  }
  __syncthreads();
  {
    int n = t >> 2, k4 = t & 3;
    u16x8 o0, o1;
    #pragma unroll
    for (int j = 0; j < 8; ++j) o0[j] = f2b(T[k4*16 + j][n]);
    #pragma unroll
    for (int j = 0; j < 8; ++j) o1[j] = f2b(T[k4*16 + 8 + j][n]);
    *(u16x8*)(lwbt + (size_t)n*4096 + kb + k4*16)     = o0;
    *(u16x8*)(lwbt + (size_t)n*4096 + kb + k4*16 + 8) = o1;
  }
}

// ---------------- k_stat0: raw-lc moments (3-dim Gram) ----------------
__global__ __launch_bounds__(256) void k_stat0(const float* lc, float* PA){
  int t = threadIdx.x;
  float a[9];
  #pragma unroll
  for (int r = 0; r < 9; ++r) a[r] = 0.f;
  size_t base = (size_t)blockIdx.x * 1024 + t;
  for (int ip = 0; ip < 4; ++ip){
    size_t p = base + (size_t)ip * 256;
    float x0 = lc[p*3], x1 = lc[p*3+1], x2 = lc[p*3+2];
    a[0]+=x0; a[1]+=x1; a[2]+=x2;
    a[3]+=x0*x0; a[4]+=x0*x1; a[5]+=x0*x2;
    a[6]+=x1*x1; a[7]+=x1*x2; a[8]+=x2*x2;
  }
  #pragma unroll
  for (int m = 1; m < 64; m <<= 1){
    #pragma unroll
    for (int r = 0; r < 9; ++r) a[r] += __shfl_xor(a[r], m);
  }
  if ((t & 63) == 0){
    float* dst = PA + (size_t)(blockIdx.x*4 + (t>>6)) * 16;
    f32x4 v0 = {a[0],a[1],a[2],a[3]}, v1 = {a[4],a[5],a[6],a[7]}, v2 = {a[8],0.f,0.f,0.f};
    *(f32x4*)dst = v0; *(f32x4*)(dst+4) = v1; *(f32x4*)(dst+8) = v2;
  }
}

// ---------------- k_red0: finalize layer0 BN from lc moments ----------------
__global__ __launch_bounds__(256) void k_red0(const float* PA, const float* w0, const float* b0,
                                              const float* g0, const float* be0, float* AD){
  __shared__ float ms[12];
  int t = threadIdx.x;
  if (t < 12){
    float s0=0,s1=0,s2=0,s3=0;
    const float* p = PA + t;
    for (int r = 0; r < 2048; r += 4){
      s0 += p[(size_t)(r+0)*16]; s1 += p[(size_t)(r+1)*16];
      s2 += p[(size_t)(r+2)*16]; s3 += p[(size_t)(r+3)*16];
    }
    ms[t] = (s0+s1)+(s2+s3);
  }
  __syncthreads();
  if (t < 16){
    float wx = w0[t*3], wy = w0[t*3+1], wz = w0[t*3+2], bb = b0[t];
    float lin = wx*ms[0] + wy*ms[1] + wz*ms[2];
    float quad = wx*wx*ms[3] + wy*wy*ms[6] + wz*wz*ms[8]
               + 2.f*(wx*wy*ms[4] + wx*wz*ms[5] + wy*wz*ms[7]);
    float S = lin + (float)NWN * bb;
    float Q = quad + 2.f*bb*lin + (float)NWN*bb*bb;
    float m = S * (1.f/NWN);
    float v = Q * (1.f/NWN) - m*m;
    float a = g0[t] * rsqrtf(v + EPSF);
    AD[t] = a; AD[16+t] = be0[t] - m*a;
  }
}

// ---------------- k_stat1_t: h0 Gram, entries [LO,HI) (+sums if SUMS) ----------------
template<int LO, int HI, bool SUMS>
__global__ __launch_bounds__(256) void k_stat1_t(const float* lc, const float* w0, const float* b0,
                                                 const float* AD, float* PB){
  __shared__ f32x4 w0p[16];
  __shared__ float a0s[16], d0s[16];
  int t = threadIdx.x;
  if (t < 16){
    f32x4 wv = {w0[t*3], w0[t*3+1], w0[t*3+2], b0[t]};
    w0p[t] = wv;
    a0s[t] = AD[t]; d0s[t] = AD[16+t];
  }
  __syncthreads();
  float G[HI-LO];
  #pragma unroll
  for (int r = 0; r < HI-LO; ++r) G[r] = 0.f;
  float sh[SUMS ? 16 : 1];
  #pragma unroll
  for (int r = 0; r < (SUMS?16:1); ++r) sh[r] = 0.f;
  size_t base = (size_t)blockIdx.x * 1024 + t;
  for (int ip = 0; ip < 4; ++ip){
    size_t p = base + (size_t)ip * 256;
    float x0 = lc[p*3], x1 = lc[p*3+1], x2 = lc[p*3+2];
    float h[16];
    #pragma unroll
    for (int oc = 0; oc < 16; ++oc){
      f32x4 w = w0p[oc];
      float y = w.x*x0 + w.y*x1 + w.z*x2 + w.w;
      h[oc] = fmaxf(0.f, a0s[oc]*y + d0s[oc]);
      if (SUMS) sh[oc] += h[oc];
    }
    int idx = 0;
    #pragma unroll
    for (int i = 0; i < 16; ++i){
      #pragma unroll
      for (int j = i; j < 16; ++j){
        if (idx >= LO && idx < HI) G[idx-LO] += h[i]*h[j];
        ++idx;
      }
    }
  }
  #pragma unroll
  for (int m = 1; m < 64; m <<= 1){
    #pragma unroll
    for (int r = 0; r < HI-LO; ++r) G[r] += __shfl_xor(G[r], m);
    if (SUMS){
      #pragma unroll
      for (int r = 0; r < 16; ++r) sh[r] += __shfl_xor(sh[r], m);
    }
  }
  if ((t & 63) == 0){
    float* dst = PB + (size_t)(blockIdx.x*4 + (t>>6)) * 160;
    #pragma unroll
    for (int r = 0; r < HI-LO; r += 4){ f32x4 v = {G[r],G[r+1],G[r+2],G[r+3]}; *(f32x4*)(dst + LO + r) = v; }
    if (SUMS){
      #pragma unroll
      for (int r = 0; r < 16; r += 4){ f32x4 v = {sh[r],sh[r+1],sh[r+2],sh[r+3]}; *(f32x4*)(dst + 136 + r) = v; }
    }
  }
}

// ---------------- k_red1: reduce h0 Gram -> layer1 BN params ----------------
__global__ __launch_bounds__(256) void k_red1(const float* PB, const float* w1, const float* b1,
                                              const float* g1, const float* be1, float* AD){
  __shared__ float red[152];
  int t = threadIdx.x;
  if (t < 152){
    float s0=0,s1=0,s2=0,s3=0,s4=0,s5=0,s6=0,s7=0;
    const float* p = PB + t;
    for (int r = 0; r < 2048; r += 8){
      s0 += p[(size_t)(r+0)*160]; s1 += p[(size_t)(r+1)*160];
      s2 += p[(size_t)(r+2)*160]; s3 += p[(size_t)(r+3)*160];
      s4 += p[(size_t)(r+4)*160]; s5 += p[(size_t)(r+5)*160];
      s6 += p[(size_t)(r+6)*160]; s7 += p[(size_t)(r+7)*160];
    }
    red[t] = ((s0+s1)+(s2+s3)) + ((s4+s5)+(s6+s7));
  }
  __syncthreads();
  if (t < 16){
    float wv[16];
    #pragma unroll
    for (int ic = 0; ic < 16; ++ic) wv[ic] = w1[t*16+ic];
    float lin = 0.f;
    #pragma unroll
    for (int ic = 0; ic < 16; ++ic) lin += wv[ic]*red[136+ic];
    float quad = 0.f; int idx = 0;
    for (int i = 0; i < 16; ++i)
      for (int j = i; j < 16; ++j){
        float M = red[idx++];
        quad += wv[i]*wv[j]*M*((i==j)?1.f:2.f);
      }
    float bb = b1[t];
    float S = lin + (float)NWN * bb;
    float Q = quad + 2.f*bb*lin + (float)NWN*bb*bb;
    float m = S * (1.f/NWN);
    float v = Q * (1.f/NWN) - m*m;
    float a = g1[t] * rsqrtf(v + EPSF);
    AD[32+t] = a; AD[48+t] = be1[t] - m*a;
  }
}

// ---------------- k_stat2_t: h1 Gram, entries [LO,HI) (+sums if SUMS) ----------------
template<int LO, int HI, bool SUMS>
__global__ __launch_bounds__(256) void k_stat2_t(const float* lc, const float* w0, const float* b0,
                                                 const float* w1, const float* b1,
                                                 const float* AD, float* PB){
  __shared__ f32x4 w0p[16];
  __shared__ float a0s[16], d0s[16];
  __shared__ float w1s[256];
  __shared__ float b1s[16], a1s[16], d1s[16];
  int t = threadIdx.x;
  if (t < 16){
    f32x4 wv = {w0[t*3], w0[t*3+1], w0[t*3+2], b0[t]};
    w0p[t] = wv;
    a0s[t] = AD[t]; d0s[t] = AD[16+t];
    b1s[t] = b1[t]; a1s[t] = AD[32+t]; d1s[t] = AD[48+t];
  }
  w1s[t] = w1[t];
  __syncthreads();
  float G[HI-LO];
  #pragma unroll
  for (int r = 0; r < HI-LO; ++r) G[r] = 0.f;
  float sh[SUMS ? 16 : 1];
  #pragma unroll
  for (int r = 0; r < (SUMS?16:1); ++r) sh[r] = 0.f;
  size_t base = (size_t)blockIdx.x * 1024 + t;
  for (int ip = 0; ip < 4; ++ip){
    size_t p = base + (size_t)ip * 256;
    float x0 = lc[p*3], x1 = lc[p*3+1], x2 = lc[p*3+2];
    float h0[16];
    #pragma unroll
    for (int oc = 0; oc < 16; ++oc){
      f32x4 w = w0p[oc];
      float y = w.x*x0 + w.y*x1 + w.z*x2 + w.w;
      h0[oc] = fmaxf(0.f, a0s[oc]*y + d0s[oc]);
    }
    float h[16];
    #pragma unroll
    for (int oc = 0; oc < 16; ++oc){
      const f32x4* wr = (const f32x4*)&w1s[oc*16];
      f32x4 wa = wr[0], wb = wr[1], wc = wr[2], wd = wr[3];
      float y = b1s[oc];
      y += wa.x*h0[0]  + wa.y*h0[1]  + wa.z*h0[2]  + wa.w*h0[3];
      y += wb.x*h0[4]  + wb.y*h0[5]  + wb.z*h0[6]  + wb.w*h0[7];
      y += wc.x*h0[8]  + wc.y*h0[9]  + wc.z*h0[10] + wc.w*h0[11];
      y += wd.x*h0[12] + wd.y*h0[13] + wd.z*h0[14] + wd.w*h0[15];
      h[oc] = fmaxf(0.f, a1s[oc]*y + d1s[oc]);
      if (SUMS) sh[oc] += h[oc];
    }
    int idx = 0;
    #pragma unroll
    for (int i = 0; i < 16; ++i){
      #pragma unroll
      for (int j = i; j < 16; ++j){
        if (idx >= LO && idx < HI) G[idx-LO] += h[i]*h[j];
        ++idx;
      }
    }
  }
  #pragma unroll
  for (int m = 1; m < 64; m <<= 1){
    #pragma unroll
    for (int r = 0; r < HI-LO; ++r) G[r] += __shfl_xor(G[r], m);
    if (SUMS){
      #pragma unroll
      for (int r = 0; r < 16; ++r) sh[r] += __shfl_xor(sh[r], m);
    }
  }
  if ((t & 63) == 0){
    float* dst = PB + (size_t)(blockIdx.x*4 + (t>>6)) * 160;
    #pragma unroll
    for (int r = 0; r < HI-LO; r += 4){ f32x4 v = {G[r],G[r+1],G[r+2],G[r+3]}; *(f32x4*)(dst + LO + r) = v; }
    if (SUMS){
      #pragma unroll
      for (int r = 0; r < 16; r += 4){ f32x4 v = {sh[r],sh[r+1],sh[r+2],sh[r+3]}; *(f32x4*)(dst + 136 + r) = v; }
    }
  }
}

// ---------------- k_red2: reduce h1 Gram -> layer2 BN params ----------------
__global__ __launch_bounds__(256) void k_red2(const float* PB, const float* w2, const float* b2,
                                              const float* g2, const float* be2, float* AD){
  __shared__ float red[152];
  int t = threadIdx.x;
  if (t < 152){
    float s0=0,s1=0,s2=0,s3=0,s4=0,s5=0,s6=0,s7=0;
    const float* p = PB + t;
    for (int r = 0; r < 2048; r += 8){
      s0 += p[(size_t)(r+0)*160]; s1 += p[(size_t)(r+1)*160];
      s2 += p[(size_t)(r+2)*160]; s3 += p[(size_t)(r+3)*160];
      s4 += p[(size_t)(r+4)*160]; s5 += p[(size_t)(r+5)*160];
      s6 += p[(size_t)(r+6)*160]; s7 += p[(size_t)(r+7)*160];
    }
    red[t] = ((s0+s1)+(s2+s3)) + ((s4+s5)+(s6+s7));
  }
  __syncthreads();
  if (t < 64){
    float wv[16];
    #pragma unroll
    for (int ic = 0; ic < 16; ++ic) wv[ic] = w2[t*16+ic];
    float lin = 0.f;
    #pragma unroll
    for (int ic = 0; ic < 16; ++ic) lin += wv[ic]*red[136+ic];
    float quad = 0.f; int idx = 0;
    for (int i = 0; i < 16; ++i)
      for (int j = i; j < 16; ++j){
        float M = red[idx++];
        quad += wv[i]*wv[j]*M*((i==j)?1.f:2.f);
      }
    float bb = b2[t];
    float S = lin + (float)NWN * bb;
    float Q = quad + 2.f*bb*lin + (float)NWN*bb*bb;
    float m = S * (1.f/NWN);
    float v = Q * (1.f/NWN) - m*m;
    float a = g2[t] * rsqrtf(v + EPSF);
    AD[64+t] = a; AD[128+t] = be2[t] - m*a;
  }
}

// ---------------- K5: one point per block — gather + WeightNet + MFMA ----------------
__global__ __launch_bounds__(256) void k_main(const float* lcg, const int* nbrg,
    const float* points, const float* xyz,
    const float* w0, const float* b0, const float* w1, const float* b1,
    const float* w2, const float* b2, const float* AD,
    u16* npw){
  __shared__ u16   Gr[32*72];          // bf16 row-major: Gr[k][i], stride 72
  __shared__ u16   Wr[32*72];          // bf16 row-major: Wr[k][o], stride 72
  __shared__ float H0s[32][17];
  __shared__ float H1s[32][20];        // stride 20 -> 16B-aligned f32x4 rows
  __shared__ float lcs[32][4];
  __shared__ int   nbr[32];
  __shared__ float w0c[48], b0c[16], a0c[16], d0c[16];
  __shared__ float w1c[16][17], b1c[16], a1c[16], d1c[16];
  __shared__ float w2c[64][17], b2c[64], a2c[64], d2c[64];
  int t = threadIdx.x;
  int point = blockIdx.x;
  int bb = point >> 10;
  if (t < 48) w0c[t] = w0[t];
  if (t < 16){
    b0c[t] = b0[t]; b1c[t] = b1[t];
    a0c[t] = AD[t];    d0c[t] = AD[16+t];
    a1c[t] = AD[32+t]; d1c[t] = AD[48+t];
  }
  w1c[t>>4][t&15] = w1[t];
  for (int i = t; i < 1024; i += 256) w2c[i>>4][i&15] = w2[i];
  if (t < 64){
    b2c[t] = b2[t];
    a2c[t] = AD[64+t]; d2c[t] = AD[128+t];
  }
  if (t < 32) nbr[t] = nbrg[(size_t)point * 32 + t];
  if (t < 96){ int k = t / 3, c = t % 3; lcs[k][c] = lcg[(size_t)point * 96 + t]; }
  __syncthreads();   // (A) weights + nbr + lcs ready

  // gather grouped -> Gr bf16 (coalesced row writes)
  {
    int k = t >> 3, c8 = t & 7;
    int n = nbr[k];
    const float* prow = points + (size_t)(bb * NN + n) * 61;
    const float* xr   = xyz    + (size_t)(bb * NN + n) * 3;
    u16x8 g;
    #pragma unroll
    for (int j = 0; j < 8; ++j){
      int c = c8 * 8 + j;
      g[j] = f2b((c < 61) ? prow[c] : xr[c - 61]);
    }
    *(u16x8*)&Gr[k*72 + c8*8] = g;
  }
  // H0
  #pragma unroll
  for (int jj = 0; jj < 2; ++jj){
    int l2 = t + jj * 256; int k = l2 >> 4, oc = l2 & 15;
    float y = w0c[oc*3]*lcs[k][0] + w0c[oc*3+1]*lcs[k][1] + w0c[oc*3+2]*lcs[k][2] + b0c[oc];
    H0s[k][oc] = fmaxf(0.f, a0c[oc]*y + d0c[oc]);
  }
  __syncthreads();   // (B) H0 ready
  // H1
  #pragma unroll
  for (int jj = 0; jj < 2; ++jj){
    int l2 = t + jj * 256; int k = l2 >> 4, oc = l2 & 15;
    float y = b1c[oc];
    #pragma unroll
    for (int ic = 0; ic < 16; ++ic) y += w1c[oc][ic] * H0s[k][ic];
    H1s[k][oc] = fmaxf(0.f, a1c[oc]*y + d1c[oc]);
  }
  __syncthreads();   // (C) H1 ready
  // W -> Wr
  {
    int o = t & 63, kb = (t >> 6) * 8;
    float wrow[16];
    #pragma unroll
    for (int ic = 0; ic < 16; ++ic) wrow[ic] = w2c[o][ic];
    float a2 = a2c[o], d2 = d2c[o], bb2 = b2c[o];
    #pragma unroll
    for (int j = 0; j < 8; ++j){
      const f32x4* hr = (const f32x4*)&H1s[kb + j][0];
      f32x4 h0v = hr[0], h1v = hr[1], h2v = hr[2], h3v = hr[3];
      float y = bb2;
      y += wrow[0]*h0v.x + wrow[1]*h0v.y + wrow[2]*h0v.z + wrow[3]*h0v.w;
      y += wrow[4]*h1v.x + wrow[5]*h1v.y + wrow[6]*h1v.z + wrow[7]*h1v.w;
      y += wrow[8]*h2v.x + wrow[9]*h2v.y + wrow[10]*h2v.z + wrow[11]*h2v.w;
      y += wrow[12]*h3v.x + wrow[13]*h3v.y + wrow[14]*h3v.z + wrow[15]*h3v.w;
      Wr[(kb + j)*72 + o] = f2b(fmaxf(0.f, a2*y + d2));
    }
  }
  __syncthreads();   // (D) Gr, Wr ready
  // MFMA: wave w owns o-tile w; all 4 i-tiles; direct global store
  {
    int w = t >> 6, l = t & 63;
    int li = l & 15, lk = (l >> 4) * 8, lr = (l >> 4) * 4;
    s16x8 bfrag;
    #pragma unroll
    for (int j = 0; j < 8; ++j) bfrag[j] = (short)Wr[(lk + j)*72 + w*16 + li];
    #pragma unroll
    for (int it = 0; it < 4; ++it){
      s16x8 afrag;
      #pragma unroll
      for (int j = 0; j < 8; ++j) afrag[j] = (short)Gr[(lk + j)*72 + it*16 + li];
      f32x4 z = {0.f, 0.f, 0.f, 0.f};
      f32x4 d = __builtin_amdgcn_mfma_f32_16x16x32_bf16(afrag, bfrag, z, 0, 0, 0);
      #pragma unroll
      for (int r = 0; r < 4; ++r)
        npw[(size_t)point*4096 + (size_t)(it*16 + lr + r)*64 + w*16 + li] = f2b(d[r]);
    }
  }
}

// ---------------- K5b: channel stats from npw (streaming, coalesced) ----------------
__global__ __launch_bounds__(256) void k_statC(const u16* npw, float* PC){
  int t = threadIdx.x;
  float s[16], q[16];
  #pragma unroll
  for (int j = 0; j < 16; ++j){ s[j] = 0.f; q[j] = 0.f; }
  size_t rowbase = (size_t)blockIdx.x * 64;
  for (int p = 0; p < 64; ++p){
    const u16* row = npw + (rowbase + p) * 4096 + t * 16;
    u16x8 a = *(const u16x8*)row;
    u16x8 b = *(const u16x8*)(row + 8);
    #pragma unroll
    for (int j = 0; j < 8; ++j){ float v = bf(a[j]); s[j]   += v; q[j]   += v*v; }
    #pragma unroll
    for (int j = 0; j < 8; ++j){ float v = bf(b[j]); s[8+j] += v; q[8+j] += v*v; }
  }
  float* dst = PC + (size_t)blockIdx.x * 8192 + t * 16;
  #pragma unroll
  for (int j = 0; j < 16; ++j){ dst[j] = s[j]; dst[4096 + j] = q[j]; }
}

// ---------------- K6b: reduce partials + finalize 4096-channel BN ----------------
__global__ __launch_bounds__(256) void k_finC(const float* PC, const float* gc, const float* bc,
                                              float* AC, float* DC){
  int ch = blockIdx.x * 256 + threadIdx.x;
  float s = 0.f, q = 0.f;
  for (int r = 0; r < 256; ++r){
    s += PC[(size_t)r * 8192 + ch];
    q += PC[(size_t)r * 8192 + 4096 + ch];
  }
  float m = s * (1.f/16384.f);
  float v = q * (1.f/16384.f) - m*m;
  float a = gc[ch] * rsqrtf(v + EPSF);
  AC[ch] = a; DC[ch] = bc[ch] - m*a;
}

// ---------------- K7: MFMA GEMM [16384,4096]x[4096,64], fused bn+relu on A ----------------
__global__ __launch_bounds__(256) void k_linear(const u16* npw, const float* AC, const float* DC,
                                                const u16* lwbt, const float* lb, float* yw){
  __shared__ u16 Al[32*72];
  __shared__ u16 Bl[64*72];
  int t = threadIdx.x;
  int w = t >> 6, l = t & 63;
  int rowbase = blockIdx.x * 32;
  int mt = w & 1, np2 = w >> 1;
  f32x4 acc0 = {0.f,0.f,0.f,0.f}, acc1 = acc0;
  for (int kb = 0; kb < 4096; kb += 64){
    __syncthreads();
    {
      int r = t >> 3, c8 = t & 7;
      int kk = kb + c8*8;
      u16x8 u = *(const u16x8*)(npw + (size_t)(rowbase + r)*4096 + kk);
      f32x4 alo = *(const f32x4*)(AC + kk), ahi = *(const f32x4*)(AC + kk + 4);
      f32x4 dlo = *(const f32x4*)(DC + kk), dhi = *(const f32x4*)(DC + kk + 4);
      u16x8 o;
      o[0] = f2b(fmaxf(0.f, alo.x*bf(u[0]) + dlo.x));
      o[1] = f2b(fmaxf(0.f, alo.y*bf(u[1]) + dlo.y));
      o[2] = f2b(fmaxf(0.f, alo.z*bf(u[2]) + dlo.z));
      o[3] = f2b(fmaxf(0.f, alo.w*bf(u[3]) + dlo.w));
      o[4] = f2b(fmaxf(0.f, ahi.x*bf(u[4]) + dhi.x));
      o[5] = f2b(fmaxf(0.f, ahi.y*bf(u[5]) + dhi.y));
      o[6] = f2b(fmaxf(0.f, ahi.z*bf(u[6]) + dhi.z));
      o[7] = f2b(fmaxf(0.f, ahi.w*bf(u[7]) + dhi.w));
      *(u16x8*)&Al[r*72 + c8*8] = o;
    }
    #pragma unroll
    for (int jj = 0; jj < 2; ++jj){
      int n = (t >> 3) + jj*32, c8 = t & 7;
      u16x8 u = *(const u16x8*)(lwbt + (size_t)n*4096 + kb + c8*8);
      *(u16x8*)&Bl[n*72 + c8*8] = u;
    }
    __syncthreads();
    #pragma unroll
    for (int ks = 0; ks < 2; ++ks){
      s16x8 af  = *(const s16x8*)&Al[(mt*16 + (l & 15))*72 + ks*32 + (l >> 4)*8];
      s16x8 bf0 = *(const s16x8*)&Bl[((np2*2    )*16 + (l & 15))*72 + ks*32 + (l >> 4)*8];
      s16x8 bf1 = *(const s16x8*)&Bl[((np2*2 + 1)*16 + (l & 15))*72 + ks*32 + (l >> 4)*8];
      acc0 = __builtin_amdgcn_mfma_f32_16x16x32_bf16(af, bf0, acc0, 0, 0, 0);
      acc1 = __builtin_amdgcn_mfma_f32_16x16x32_bf16(af, bf1, acc1, 0, 0, 0);
    }
  }
  int col0 = np2*32 + (l & 15), col1 = col0 + 16;
  float lb0 = lb[col0], lb1 = lb[col1];
  #pragma unroll
  for (int r = 0; r < 4; ++r){
    int row = rowbase + mt*16 + (l >> 4)*4 + r;
    yw[(size_t)row*64 + col0] = acc0[r] + lb0;
    yw[(size_t)row*64 + col1] = acc1[r] + lb1;
  }
}

// ---------------- K8a: final-BN stats -> block partials ----------------
__global__ __launch_bounds__(256) void k_statL(const float* yw, float* PL){
  __shared__ float sh[4][128];
  int t = threadIdx.x;
  int o = t & 63;
  int w = t >> 6;
  int rg = blockIdx.x * 4 + w;
  float s = 0.f, q = 0.f;
  for (int r = rg * 64; r < rg * 64 + 64; ++r){
    float v = yw[(size_t)r * 64 + o];
    s += v; q += v*v;
  }
  sh[w][o] = s; sh[w][64+o] = q;
  __syncthreads();
  if (t < 128) PL[blockIdx.x*128 + t] = sh[0][t] + sh[1][t] + sh[2][t] + sh[3][t];
}

__global__ __launch_bounds__(128) void k_redL(const float* PL, float* SL){
  int t = threadIdx.x;
  float s = 0.f;
  for (int b = 0; b < 64; ++b) s += PL[b*128 + t];
  SL[t] = s;
}

__global__ __launch_bounds__(256) void k_final(const float* yw, const float* SL,
                                               const float* gl, const float* bl, float* out){
  int gid = blockIdx.x * 256 + threadIdx.x;
  int o = gid & 63;
  float m = SL[o] * (1.f/16384.f);
  float v = SL[64 + o] * (1.f/16384.f) - m*m;
  float a = gl[o] * rsqrtf(v + EPSF);
  float d = bl[o] - m*a;
  float y = fmaxf(0.f, a * yw[gid] + d);
  out[49152 + gid] = y;
}

extern "C" void kernel_launch(void* const* d_in, const int* in_sizes, int n_in,
                              void* d_out, int out_size, void* d_ws, size_t ws_size,
                              hipStream_t stream){
  (void)in_sizes; (void)n_in; (void)out_size; (void)ws_size;
  const float* xyz    = (const float*)d_in[0];
  const float* points = (const float*)d_in[1];
  const float* lc     = (const float*)d_in[2];
  const int*   nbrl   = (const int*)d_in[3];
  const int*   didx   = (const int*)d_in[4];
  const float* w0 = (const float*)d_in[5];
  const float* b0 = (const float*)d_in[6];
  const float* g0 = (const float*)d_in[7];
  const float* be0= (const float*)d_in[8];
  const float* w1 = (const float*)d_in[9];
  const float* b1 = (const float*)d_in[10];
  const float* g1 = (const float*)d_in[11];
  const float* be1= (const float*)d_in[12];
  const float* w2 = (const float*)d_in[13];
  const float* b2 = (const float*)d_in[14];
  const float* g2 = (const float*)d_in[15];
  const float* be2= (const float*)d_in[16];
  const float* gc = (const float*)d_in[17];
  const float* bc = (const float*)d_in[18];
  const float* lw = (const float*)d_in[19];
  const float* lb = (const float*)d_in[20];
  const float* gl = (const float*)d_in[21];
  const float* bl = (const float*)d_in[22];
  float* out = (float*)d_out;
  char* ws = (char*)d_ws;

  float* AD  = (float*)ws;           // 192
  float* SL  = AD + 192;             // 128
  float* AC  = SL + 128;             // 4096
  float* DC  = AC + 4096;            // 4096
  float* PL  = DC + 4096;            // 8192
  float* PA  = PL + 8192;            // 2048*16 = 32768
  float* PB1 = PA + 32768;           // 2048*160 = 327680
  float* PB2 = PB1 + 327680;         // 327680
  float* PC  = (float*)(ws + 4194304);                        // 8 MB
  u16*  npw  = (u16*)(ws + 4194304 + 8388608);                // 128 MB bf16
  float* yw  = (float*)(ws + 4194304 + 8388608 + 134217728);  // 4 MB f32
  u16*  lwbt = (u16*)(ws + 4194304 + 8388608 + 134217728 + 4194304); // 512 KB

  k_newxyz <<<64,    256, 0, stream>>>(xyz, didx, out);
  k_prep   <<<64,    256, 0, stream>>>(lw, lwbt);
  k_stat0  <<<512,   256, 0, stream>>>(lc, PA);
  k_red0   <<<1,     256, 0, stream>>>(PA, w0, b0, g0, be0, AD);
  k_stat1_t<0,68,true>   <<<512, 256, 0, stream>>>(lc, w0, b0, AD, PB1);
  k_stat1_t<68,136,false><<<512, 256, 0, stream>>>(lc, w0, b0, AD, PB1);
  k_red1   <<<1,     256, 0, stream>>>(PB1, w1, b1, g1, be1, AD);
  k_stat2_t<0,68,true>   <<<512, 256, 0, stream>>>(lc, w0, b0, w1, b1, AD, PB2);
  k_stat2_t<68,136,false><<<512, 256, 0, stream>>>(lc, w0, b0, w1, b1, AD, PB2);
  k_red2   <<<1,     256, 0, stream>>>(PB2, w2, b2, g2, be2, AD);
  k_main   <<<16384, 256, 0, stream>>>(lc, nbrl, points, xyz,
                                       w0, b0, w1, b1, w2, b2, AD, npw);
  k_statC  <<<256,   256, 0, stream>>>(npw, PC);
  k_finC   <<<16,    256, 0, stream>>>(PC, gc, bc, AC, DC);
  k_linear <<<512,   256, 0, stream>>>(npw, AC, DC, lwbt, lb, yw);
  k_statL  <<<64,    256, 0, stream>>>(yw, PL);
  k_redL   <<<1,     128, 0, stream>>>(PL, SL);
  k_final  <<<4096,  256, 0, stream>>>(yw, SL, gl, bl, out);
}